// Round 1
// baseline (138.559 us; speedup 1.0000x reference)
//
#include <hip/hip_runtime.h>

#define GXD 96
#define GYD 96
#define GZD 96

__global__ __launch_bounds__(256) void sdf_grid_kernel(
    const float* __restrict__ sdfs,       // (M, stride)
    const int*   __restrict__ sdf_shapes, // (M, 3)
    const int*   __restrict__ indices,    // (B, N)
    const float* __restrict__ poses,      // (B, N, 7)
    const float* __restrict__ widths,     // (B, N, 3)
    float*       __restrict__ out,        // (B, 96, 96, 96)
    int total, int N, int sdf_stride)
{
    int idx = blockIdx.x * blockDim.x + threadIdx.x;
    if (idx >= total) return;

    int z = idx % GZD;
    int y = (idx / GZD) % GYD;
    int x = (idx / (GZD * GYD)) % GXD;
    int b = idx / (GZD * GYD * GXD);

    const float LOWER = -1.2f;
    const float STEP  = 0.025f;
    float px = LOWER + ((float)x + 0.5f) * STEP;
    float py = LOWER + ((float)y + 0.5f) * STEP;
    float pz = LOWER + ((float)z + 0.5f) * STEP;

    float best = 1e10f;

    for (int n = 0; n < N; ++n) {
        int bn = b * N + n;
        int m  = indices[bn];

        const float* pp = poses + (size_t)bn * 7;
        float tx = pp[0], ty = pp[1], tz = pp[2];
        float qx = pp[3], qy = pp[4], qz = pp[5], qw = pp[6];

        // normalize quaternion (match reference: q / norm, true divisions)
        float nrm = sqrtf(qx * qx + qy * qy + qz * qz + qw * qw);
        qx = qx / nrm; qy = qy / nrm; qz = qz / nrm; qw = qw / nrm;

        // d = p - t
        float dx = px - tx, dy = py - ty, dz = pz - tz;

        // rotate_inv: u = -q.xyz; uv = cross(u,d); r = d + 2*cross(u, uv + w*d)
        float ux = -qx, uy = -qy, uz = -qz;
        float uvx = uy * dz - uz * dy;
        float uvy = uz * dx - ux * dz;
        float uvz = ux * dy - uy * dx;
        float t2x = uvx + qw * dx;
        float t2y = uvy + qw * dy;
        float t2z = uvz + qw * dz;
        float rx = dx + 2.0f * (uy * t2z - uz * t2y);
        float ry = dy + 2.0f * (uz * t2x - ux * t2z);
        float rz = dz + 2.0f * (ux * t2y - uy * t2x);

        const float* ww = widths + (size_t)bn * 3;
        float gx = rx / ww[0] - 0.5f;
        float gy = ry / ww[1] - 0.5f;
        float gz = rz / ww[2] - 0.5f;

        int SX = sdf_shapes[m * 3 + 0];
        int SY = sdf_shapes[m * 3 + 1];
        int SZ = sdf_shapes[m * 3 + 2];
        float mx = (float)(SX - 1);
        float my = (float)(SY - 1);
        float mz = (float)(SZ - 1);

        bool inside = (gx >= 0.0f) && (gx <= mx) &&
                      (gy >= 0.0f) && (gy <= my) &&
                      (gz >= 0.0f) && (gz <= mz);

        float fx = fminf(fmaxf(gx, 0.0f), mx);
        float fy = fminf(fmaxf(gy, 0.0f), my);
        float fz = fminf(fmaxf(gz, 0.0f), mz);

        int i0x = (int)floorf(fx);
        int i0y = (int)floorf(fy);
        int i0z = (int)floorf(fz);
        float frx = fx - (float)i0x;
        float fry = fy - (float)i0y;
        float frz = fz - (float)i0z;

        int i1x = min(i0x + 1, SX - 1);
        int i1y = min(i0y + 1, SY - 1);
        int i1z = min(i0z + 1, SZ - 1);

        const float* sd = sdfs + (size_t)m * sdf_stride;

        int base00 = (i0x * SY + i0y) * SZ;
        int base01 = (i0x * SY + i1y) * SZ;
        int base10 = (i1x * SY + i0y) * SZ;
        int base11 = (i1x * SY + i1y) * SZ;

        float v000 = sd[base00 + i0z];
        float v001 = sd[base00 + i1z];
        float v010 = sd[base01 + i0z];
        float v011 = sd[base01 + i1z];
        float v100 = sd[base10 + i0z];
        float v101 = sd[base10 + i1z];
        float v110 = sd[base11 + i0z];
        float v111 = sd[base11 + i1z];

        float wx0 = 1.0f - frx, wx1 = frx;
        float wy0 = 1.0f - fry, wy1 = fry;
        float wz0 = 1.0f - frz, wz1 = frz;

        float acc = wx0 * wy0 * wz0 * v000
                  + wx0 * wy0 * wz1 * v001
                  + wx0 * wy1 * wz0 * v010
                  + wx0 * wy1 * wz1 * v011
                  + wx1 * wy0 * wz0 * v100
                  + wx1 * wy0 * wz1 * v101
                  + wx1 * wy1 * wz0 * v110
                  + wx1 * wy1 * wz1 * v111;

        float val = inside ? acc : 1e10f;
        best = fminf(best, val);
    }

    out[idx] = best;
}

extern "C" void kernel_launch(void* const* d_in, const int* in_sizes, int n_in,
                              void* d_out, int out_size, void* d_ws, size_t ws_size,
                              hipStream_t stream) {
    const float* sdfs    = (const float*)d_in[0];
    const int*   shapes  = (const int*)d_in[1];
    const int*   indices = (const int*)d_in[2];
    const float* poses   = (const float*)d_in[3];
    const float* widths  = (const float*)d_in[4];
    float*       out     = (float*)d_out;

    int M = in_sizes[1] / 3;                // sdf_shapes is (M,3)
    int sdf_stride = in_sizes[0] / M;       // elements per SDF volume
    int B = out_size / (GXD * GYD * GZD);
    int N = in_sizes[2] / B;                // indices is (B,N)

    int total = out_size;
    int threads = 256;
    int blocks = (total + threads - 1) / threads;
    sdf_grid_kernel<<<blocks, threads, 0, stream>>>(
        sdfs, shapes, indices, poses, widths, out, total, N, sdf_stride);
}

// Round 2
// 34.346 us; speedup vs baseline: 4.0342x; 4.0342x over previous
//
#include <hip/hip_runtime.h>

#define GXD 96
#define GYD 96
#define GZD 96
#define PTS_PER_B (GXD * GYD * GZD)
#define RECSZ 24  // floats per (b,n) record

// record layout:
// f[0..2]  = t
// f[3..6]  = normalized q
// f[7..9]  = w
// f[10..12]= (S-1) as float
// f[13..15]= conservative lower bound on local coord (0.499*w)
// f[16..18]= conservative upper bound ((m+0.501)*w)
// i[19..21]= SX, SY, SZ
// i[22]    = m * sdf_stride (base offset into sdfs)
__global__ void prep_records(const int* __restrict__ shapes,
                             const int* __restrict__ indices,
                             const float* __restrict__ poses,
                             const float* __restrict__ widths,
                             float* __restrict__ rec,
                             int BN, int sdf_stride)
{
    int bn = blockIdx.x * blockDim.x + threadIdx.x;
    if (bn >= BN) return;
    int m = indices[bn];
    const float* pp = poses + (size_t)bn * 7;
    float tx = pp[0], ty = pp[1], tz = pp[2];
    float qx = pp[3], qy = pp[4], qz = pp[5], qw = pp[6];
    // identical op order to the validated round-0 kernel -> bit-identical q
    float nrm = sqrtf(qx * qx + qy * qy + qz * qz + qw * qw);
    qx = qx / nrm; qy = qy / nrm; qz = qz / nrm; qw = qw / nrm;
    float wx = widths[bn * 3 + 0], wy = widths[bn * 3 + 1], wz = widths[bn * 3 + 2];
    int SX = shapes[m * 3 + 0], SY = shapes[m * 3 + 1], SZ = shapes[m * 3 + 2];
    float mx = (float)(SX - 1), my = (float)(SY - 1), mz = (float)(SZ - 1);

    float* r = rec + (size_t)bn * RECSZ;
    r[0] = tx; r[1] = ty; r[2] = tz;
    r[3] = qx; r[4] = qy; r[5] = qz; r[6] = qw;
    r[7] = wx; r[8] = wy; r[9] = wz;
    r[10] = mx; r[11] = my; r[12] = mz;
    // margin 1e-3 in g-units >> division/FMA rounding (~1e-7 rel); widths > 0
    r[13] = 0.499f * wx;
    r[14] = 0.499f * wy;
    r[15] = 0.499f * wz;
    r[16] = (mx + 0.501f) * wx;
    r[17] = (my + 0.501f) * wy;
    r[18] = (mz + 0.501f) * wz;
    int* ri = (int*)r;
    ri[19] = SX; ri[20] = SY; ri[21] = SZ;
    ri[22] = m * sdf_stride;
}

__global__ __launch_bounds__(256) void sdf_grid_fast(
    const float* __restrict__ sdfs,
    const float* __restrict__ rec,
    float* __restrict__ out,
    int N)
{
    int pid = blockIdx.x * blockDim.x + threadIdx.x;  // 0 .. 96^3-1
    int b = blockIdx.y;

    int z = pid % GZD;
    int y = (pid / GZD) % GYD;
    int x = pid / (GZD * GYD);

    const float LOWER = -1.2f;
    const float STEP  = 0.025f;
    float px = LOWER + ((float)x + 0.5f) * STEP;
    float py = LOWER + ((float)y + 0.5f) * STEP;
    float pz = LOWER + ((float)z + 0.5f) * STEP;

    float best = 1e10f;

    for (int n = 0; n < N; ++n) {
        const float* r = rec + (size_t)(b * N + n) * RECSZ;  // wave-uniform address
        float dx = px - r[0], dy = py - r[1], dz = pz - r[2];
        float qx = r[3], qy = r[4], qz = r[5], qw = r[6];

        float ux = -qx, uy = -qy, uz = -qz;
        float uvx = uy * dz - uz * dy;
        float uvy = uz * dx - ux * dz;
        float uvz = ux * dy - uy * dx;
        float t2x = uvx + qw * dx;
        float t2y = uvy + qw * dy;
        float t2z = uvz + qw * dz;
        float rx = dx + 2.0f * (uy * t2z - uz * t2y);
        float ry = dy + 2.0f * (uz * t2x - ux * t2z);
        float rz = dz + 2.0f * (ux * t2y - uy * t2x);

        // conservative (strictly more permissive) box pre-test without division
        bool maybe = (rx >= r[13]) & (rx <= r[16]) &
                     (ry >= r[14]) & (ry <= r[17]) &
                     (rz >= r[15]) & (rz <= r[18]);
        if (maybe) {
            float gx = rx / r[7] - 0.5f;
            float gy = ry / r[8] - 0.5f;
            float gz = rz / r[9] - 0.5f;
            float mx = r[10], my = r[11], mz = r[12];
            // exact inside test: identical ops to validated round-0 kernel
            bool inside = (gx >= 0.0f) & (gx <= mx) &
                          (gy >= 0.0f) & (gy <= my) &
                          (gz >= 0.0f) & (gz <= mz);
            if (inside) {
                const int* ri = (const int*)r;
                int SX = ri[19], SY = ri[20], SZ = ri[21];

                int i0x = (int)floorf(gx);
                int i0y = (int)floorf(gy);
                int i0z = (int)floorf(gz);
                float frx = gx - (float)i0x;
                float fry = gy - (float)i0y;
                float frz = gz - (float)i0z;
                int i1x = min(i0x + 1, SX - 1);
                int i1y = min(i0y + 1, SY - 1);
                int i1z = min(i0z + 1, SZ - 1);

                const float* sd = sdfs + ri[22];
                int b00 = (i0x * SY + i0y) * SZ;
                int b01 = (i0x * SY + i1y) * SZ;
                int b10 = (i1x * SY + i0y) * SZ;
                int b11 = (i1x * SY + i1y) * SZ;

                float v000 = sd[b00 + i0z];
                float v001 = sd[b00 + i1z];
                float v010 = sd[b01 + i0z];
                float v011 = sd[b01 + i1z];
                float v100 = sd[b10 + i0z];
                float v101 = sd[b10 + i1z];
                float v110 = sd[b11 + i0z];
                float v111 = sd[b11 + i1z];

                float c00 = v000 + frz * (v001 - v000);
                float c01 = v010 + frz * (v011 - v010);
                float c10 = v100 + frz * (v101 - v100);
                float c11 = v110 + frz * (v111 - v110);
                float c0  = c00 + fry * (c01 - c00);
                float c1  = c10 + fry * (c11 - c10);
                float acc = c0 + frx * (c1 - c0);

                best = fminf(best, acc);
            }
        }
    }

    out[(size_t)b * PTS_PER_B + pid] = best;
}

// fallback (round-0 validated kernel) in case ws is too small
__global__ __launch_bounds__(256) void sdf_grid_kernel(
    const float* __restrict__ sdfs,
    const int*   __restrict__ sdf_shapes,
    const int*   __restrict__ indices,
    const float* __restrict__ poses,
    const float* __restrict__ widths,
    float*       __restrict__ out,
    int total, int N, int sdf_stride)
{
    int idx = blockIdx.x * blockDim.x + threadIdx.x;
    if (idx >= total) return;

    int z = idx % GZD;
    int y = (idx / GZD) % GYD;
    int x = (idx / (GZD * GYD)) % GXD;
    int b = idx / (GZD * GYD * GXD);

    const float LOWER = -1.2f;
    const float STEP  = 0.025f;
    float px = LOWER + ((float)x + 0.5f) * STEP;
    float py = LOWER + ((float)y + 0.5f) * STEP;
    float pz = LOWER + ((float)z + 0.5f) * STEP;

    float best = 1e10f;

    for (int n = 0; n < N; ++n) {
        int bn = b * N + n;
        int m  = indices[bn];

        const float* pp = poses + (size_t)bn * 7;
        float tx = pp[0], ty = pp[1], tz = pp[2];
        float qx = pp[3], qy = pp[4], qz = pp[5], qw = pp[6];

        float nrm = sqrtf(qx * qx + qy * qy + qz * qz + qw * qw);
        qx = qx / nrm; qy = qy / nrm; qz = qz / nrm; qw = qw / nrm;

        float dx = px - tx, dy = py - ty, dz = pz - tz;

        float ux = -qx, uy = -qy, uz = -qz;
        float uvx = uy * dz - uz * dy;
        float uvy = uz * dx - ux * dz;
        float uvz = ux * dy - uy * dx;
        float t2x = uvx + qw * dx;
        float t2y = uvy + qw * dy;
        float t2z = uvz + qw * dz;
        float rx = dx + 2.0f * (uy * t2z - uz * t2y);
        float ry = dy + 2.0f * (uz * t2x - ux * t2z);
        float rz = dz + 2.0f * (ux * t2y - uy * t2x);

        const float* ww = widths + (size_t)bn * 3;
        float gx = rx / ww[0] - 0.5f;
        float gy = ry / ww[1] - 0.5f;
        float gz = rz / ww[2] - 0.5f;

        int SX = sdf_shapes[m * 3 + 0];
        int SY = sdf_shapes[m * 3 + 1];
        int SZ = sdf_shapes[m * 3 + 2];
        float mx = (float)(SX - 1);
        float my = (float)(SY - 1);
        float mz = (float)(SZ - 1);

        bool inside = (gx >= 0.0f) && (gx <= mx) &&
                      (gy >= 0.0f) && (gy <= my) &&
                      (gz >= 0.0f) && (gz <= mz);

        float fx = fminf(fmaxf(gx, 0.0f), mx);
        float fy = fminf(fmaxf(gy, 0.0f), my);
        float fz = fminf(fmaxf(gz, 0.0f), mz);

        int i0x = (int)floorf(fx);
        int i0y = (int)floorf(fy);
        int i0z = (int)floorf(fz);
        float frx = fx - (float)i0x;
        float fry = fy - (float)i0y;
        float frz = fz - (float)i0z;

        int i1x = min(i0x + 1, SX - 1);
        int i1y = min(i0y + 1, SY - 1);
        int i1z = min(i0z + 1, SZ - 1);

        const float* sd = sdfs + (size_t)m * sdf_stride;

        int base00 = (i0x * SY + i0y) * SZ;
        int base01 = (i0x * SY + i1y) * SZ;
        int base10 = (i1x * SY + i0y) * SZ;
        int base11 = (i1x * SY + i1y) * SZ;

        float v000 = sd[base00 + i0z];
        float v001 = sd[base00 + i1z];
        float v010 = sd[base01 + i0z];
        float v011 = sd[base01 + i1z];
        float v100 = sd[base10 + i0z];
        float v101 = sd[base10 + i1z];
        float v110 = sd[base11 + i0z];
        float v111 = sd[base11 + i1z];

        float wx0 = 1.0f - frx, wx1 = frx;
        float wy0 = 1.0f - fry, wy1 = fry;
        float wz0 = 1.0f - frz, wz1 = frz;

        float acc = wx0 * wy0 * wz0 * v000
                  + wx0 * wy0 * wz1 * v001
                  + wx0 * wy1 * wz0 * v010
                  + wx0 * wy1 * wz1 * v011
                  + wx1 * wy0 * wz0 * v100
                  + wx1 * wy0 * wz1 * v101
                  + wx1 * wy1 * wz0 * v110
                  + wx1 * wy1 * wz1 * v111;

        float val = inside ? acc : 1e10f;
        best = fminf(best, val);
    }

    out[idx] = best;
}

extern "C" void kernel_launch(void* const* d_in, const int* in_sizes, int n_in,
                              void* d_out, int out_size, void* d_ws, size_t ws_size,
                              hipStream_t stream) {
    const float* sdfs    = (const float*)d_in[0];
    const int*   shapes  = (const int*)d_in[1];
    const int*   indices = (const int*)d_in[2];
    const float* poses   = (const float*)d_in[3];
    const float* widths  = (const float*)d_in[4];
    float*       out     = (float*)d_out;

    int M = in_sizes[1] / 3;           // sdf_shapes is (M,3)
    int sdf_stride = in_sizes[0] / M;  // elements per SDF volume
    int B = out_size / PTS_PER_B;
    int N = in_sizes[2] / B;           // indices is (B,N)
    int BN = B * N;

    size_t ws_needed = (size_t)BN * RECSZ * sizeof(float);
    if (ws_size >= ws_needed && (PTS_PER_B % 256) == 0) {
        float* rec = (float*)d_ws;
        int pthreads = 64;
        int pblocks = (BN + pthreads - 1) / pthreads;
        prep_records<<<pblocks, pthreads, 0, stream>>>(
            shapes, indices, poses, widths, rec, BN, sdf_stride);
        dim3 grid(PTS_PER_B / 256, B);
        sdf_grid_fast<<<grid, 256, 0, stream>>>(sdfs, rec, out, N);
    } else {
        int total = out_size;
        int threads = 256;
        int blocks = (total + threads - 1) / threads;
        sdf_grid_kernel<<<blocks, threads, 0, stream>>>(
            sdfs, shapes, indices, poses, widths, out, total, N, sdf_stride);
    }
}